// Round 24
// baseline (239.168 us; speedup 1.0000x reference)
//
#include <hip/hip_runtime.h>
#include <hip/hip_bf16.h>
#include <math.h>

// Problem constants (FavorPlusAttention): B=2, T=4096, d=1024, h=16, dk=64, m=256
#define BB 2
#define TT 4096
#define DD 1024
#define NH 16
#define DK 64
#define MM 256
#define BT (BB*TT)        // 8192 rows
#define FEPS 1e-6f

typedef _Float16 f16x8 __attribute__((ext_vector_type(8)));
using f32x4 = __attribute__((ext_vector_type(4))) float;

#define GL2LDS16(g, l) __builtin_amdgcn_global_load_lds( \
    (const __attribute__((address_space(1))) void*)(g), \
    (__attribute__((address_space(3))) void*)(l), 16, 0, 0)

static __device__ __forceinline__ unsigned short f16bits(_Float16 v) {
    union { _Float16 f; unsigned short u; } c; c.f = v; return c.u;
}
static __device__ __forceinline__ float f16tof(unsigned u) {
    union { unsigned short s; _Float16 f; } c; c.s = (unsigned short)u; return (float)c.f;
}
// pairwise-duplicate 4 f16 (uint2) -> f16x8  [verified operand pattern]
static __device__ __forceinline__ f16x8 dup8(uint2 v) {
    union { unsigned int u[4]; f16x8 f; } o;
    o.u[0] = __builtin_amdgcn_perm(v.x, v.x, 0x01000100u);
    o.u[1] = __builtin_amdgcn_perm(v.x, v.x, 0x03020302u);
    o.u[2] = __builtin_amdgcn_perm(v.y, v.y, 0x01000100u);
    o.u[3] = __builtin_amdgcn_perm(v.y, v.y, 0x03020302u);
    return o.f;
}

// ---------------------------------------------------------------------------
// hi-only split: src [rows][1024] f32 -> dst [rows][1024] u16 (f16 hi)
// ---------------------------------------------------------------------------
__global__ __launch_bounds__(256) void split_h(const float* __restrict__ src,
                                               unsigned short* __restrict__ dst)
{
    const int rr = blockIdx.x;
    const int c = threadIdx.x * 4;
    float4 v = *(const float4*)(src + (size_t)rr * 1024 + c);
    float f[4] = {v.x, v.y, v.z, v.w};
    union { unsigned short h[4]; uint2 u; } hv;
#pragma unroll
    for (int i = 0; i < 4; i++) hv.h[i] = f16bits((_Float16)f[i]);
    *(uint2*)(dst + (size_t)rr * 1024 + c) = hv.u;
}

// hi-only fp16 weight cast: 3 weights -> [3][1024][1024] f16 (B-operand).
__global__ __launch_bounds__(256) void split_w3h(const float* __restrict__ W0,
                                                 const float* __restrict__ W1,
                                                 const float* __restrict__ W2,
                                                 unsigned short* __restrict__ dst)
{
    const int rr = blockIdx.x;           // 0..3071
    const int wi = rr >> 10, r2 = rr & 1023;
    const float* W = (wi == 0) ? W0 : (wi == 1) ? W1 : W2;
    const int c = threadIdx.x * 4;
    float4 v = *(const float4*)(W + (size_t)r2 * 1024 + c);
    float f[4] = {v.x, v.y, v.z, v.w};
    union { _Float16 h[4]; uint2 u; } hv;
#pragma unroll
    for (int i = 0; i < 4; i++) hv.h[i] = (_Float16)f[i];
    *(uint2*)(dst + (size_t)rr * 1024 + c) = hv.u;
}

// proj f32 [16][256][64] -> f16 hi [16][256][64]
__global__ __launch_bounds__(256) void pack_proj(const float* __restrict__ proj,
                                                 unsigned short* __restrict__ projh)
{
    const int idx = (blockIdx.x * 256 + threadIdx.x) * 4;   // 65536*4 = 262144
    float4 v = *(const float4*)(proj + idx);
    float f[4] = {v.x, v.y, v.z, v.w};
    union { _Float16 h[4]; uint2 u; } hv;
#pragma unroll
    for (int i = 0; i < 4; i++) hv.h[i] = (_Float16)f[i];
    *(uint2*)(projh + idx) = hv.u;
}

// ---------------------------------------------------------------------------
// gemm_h v3 (R23, resubmitted R24 after infra failure): pure f16-hi GEMM,
// 3-BUFFER ROTATION + COUNTED vmcnt.
// C = scale*(A_hi@B_hi^T)(+bias). 128x128 tile, BK=32, 4 waves, LDS 48 KB
// (3 x (8K A + 8K B)), 3 blocks/CU.
// R22's vmcnt(0) drain waited on loads issued ~160cy earlier vs ~900cy HBM
// latency -> every wave ate the difference each drain (MfmaUtil stuck at 28).
// v3: stage tile t+3 into the buffer just read; wait vmcnt(8) = tile t's 4
// loads issued THREE iterations ago (near-free). Per tile:
//   vmcnt(8) -> barrier1 (vmcnt is per-wave: own-loads-done must precede the
//   cross-wave read barrier) -> ds_read buf c -> lgkm0 -> barrier2 ->
//   stage(t+3 -> buf c) -> 16 MFMAs.
// Tail: clamped stages keep vmcnt counting exact (junk lands in dead bufs).
// MFMA order tile-sequential -> bit-identical to R15/R22.
// ---------------------------------------------------------------------------
__global__ __launch_bounds__(256, 3) void gemm_h(
    const unsigned short* __restrict__ A,
    const unsigned short* __restrict__ B0, const unsigned short* __restrict__ B1,
    const unsigned short* __restrict__ B2,
    float* __restrict__ C0, float* __restrict__ C1, float* __restrict__ C2,
    const float* __restrict__ bias,
    float sc0, float sc1, float sc2, int packMask)
{
    extern __shared__ char smem[];   // 49152: A bufs [0,24K), B bufs [24K,48K)

    // ---- XCD-grouping remap (R11) ----
    const int gx = gridDim.x, gy = gridDim.y;
    const int flat = blockIdx.y * gx + blockIdx.x;
    const int k8 = flat & 7, j8 = flat >> 3;
    const int yy = k8 * (gy >> 3) + j8 / gx;
    const int xx = j8 - (j8 / gx) * gx;

    const int which = xx >> 3;
    const int col0 = (xx & 7) * 128;
    const int row0 = yy * 128;
    const unsigned short* Bp = (which == 0) ? B0 : (which == 1) ? B1 : B2;
    float* Cp = (which == 0) ? C0 : (which == 1) ? C1 : C2;
    const float scl = (which == 0) ? sc0 : (which == 1) ? sc1 : sc2;
    const int packC = (packMask >> which) & 1;

    const int tid = threadIdx.x;             // 0..255
    const int w = tid >> 6, lane = tid & 63;
    const int wm = w >> 1, wn = w & 1;       // 2M x 2N wave grid
    const int r = lane & 15, q = lane >> 4;

    const unsigned short* aP[2];
    const unsigned short* bP[2];
    int dstO[2];
#pragma unroll
    for (int i = 0; i < 2; i++) {
        int s = tid + i * 256;
        int row = s >> 2, c = s & 3;
        aP[i] = A + (size_t)(row0 + row) * 1024 + ((c ^ (row & 3)) * 8);
        bP[i] = Bp + (size_t)(col0 + row) * 1024 + ((c ^ (row & 3)) * 8);
        dstO[i] = (i * 256 + w * 64) * 16;
    }

    auto stA = [&](int buf, int kt) {
        char* base = smem + buf * 8192;
        GL2LDS16(aP[0] + kt * 32, base + dstO[0]);
        GL2LDS16(aP[1] + kt * 32, base + dstO[1]);
    };
    auto stB = [&](int buf, int kt) {
        char* base = smem + 24576 + buf * 8192;
        GL2LDS16(bP[0] + kt * 32, base + dstO[0]);
        GL2LDS16(bP[1] + kt * 32, base + dstO[1]);
    };

    const int aRow = (wm * 64 + r) * 64;     // + mf*1024
    const int bRow = (wn * 64 + r) * 64;     // + nf*1024
    const int kx = (q ^ (r & 3)) * 16;

    f32x4 acc[4][4];
#pragma unroll
    for (int i = 0; i < 4; i++)
#pragma unroll
        for (int j = 0; j < 4; j++) acc[i][j] = (f32x4){0.f, 0.f, 0.f, 0.f};

    // ---- prologue: stage tiles 0,1,2 into bufs 0,1,2 (12 loads in flight) ----
    stA(0, 0); stB(0, 0);
    stA(1, 1); stB(1, 1);
    stA(2, 2); stB(2, 2);

    int bufc = 0;
    for (int t = 0; t < 32; ++t) {
        asm volatile("s_waitcnt vmcnt(8)" ::: "memory");   // tile t's 4 landed
        __builtin_amdgcn_s_barrier();          // barrier1: all waves' tile-t data in LDS
        const int ab = bufc * 8192;
        const int bb = 24576 + bufc * 8192;
        f16x8 af[4], bf[4];
#pragma unroll
        for (int mf = 0; mf < 4; ++mf)
            af[mf] = *(const f16x8*)(smem + ab + aRow + mf * 1024 + kx);
#pragma unroll
        for (int nf = 0; nf < 4; ++nf)
            bf[nf] = *(const f16x8*)(smem + bb + bRow + nf * 1024 + kx);
        asm volatile("s_waitcnt lgkmcnt(0)" ::: "memory");
        __builtin_amdgcn_sched_barrier(0);
        __builtin_amdgcn_s_barrier();          // barrier2: all waves done reading buf c
        const int kt = (t + 3 < 32) ? t + 3 : 31;   // clamp keeps vmcnt count exact
        stA(bufc, kt);                         // refill just-read buffer
        stB(bufc, kt);
        __builtin_amdgcn_s_setprio(1);
#pragma unroll
        for (int mf = 0; mf < 4; ++mf)
#pragma unroll
            for (int nf = 0; nf < 4; ++nf)
                acc[mf][nf] = __builtin_amdgcn_mfma_f32_16x16x32_f16(
                    af[mf], bf[nf], acc[mf][nf], 0, 0, 0);
        __builtin_amdgcn_s_setprio(0);
        bufc = (bufc == 2) ? 0 : bufc + 1;
    }
    asm volatile("s_waitcnt vmcnt(0)" ::: "memory");   // drain tail junk loads

    // ---- epilogue: C/D layout col = lane&15, row = (lane>>4)*4 + reg ----
    float bv[4];
#pragma unroll
    for (int nf = 0; nf < 4; ++nf) {
        int gcol = col0 + wn * 64 + nf * 16 + r;
        bv[nf] = bias ? bias[gcol] : 0.f;
    }
#pragma unroll
    for (int mf = 0; mf < 4; ++mf) {
        const int grow = row0 + wm * 64 + mf * 16 + q * 4;
#pragma unroll
        for (int rr = 0; rr < 4; ++rr) {
            if (packC) {
                unsigned int* Crow = (unsigned int*)Cp + (size_t)(grow + rr) * 1024;
#pragma unroll
                for (int nf = 0; nf < 4; ++nf) {
                    int gcol = col0 + wn * 64 + nf * 16 + r;
                    float v = acc[mf][nf][rr] * scl;
                    _Float16 hh = (_Float16)v;
                    _Float16 ll = (_Float16)(v - (float)hh);
                    Crow[gcol] = (unsigned int)f16bits(hh)
                               | ((unsigned int)f16bits(ll) << 16);
                }
            } else {
                float* Crow = Cp + (size_t)(grow + rr) * 1024;
#pragma unroll
                for (int nf = 0; nf < 4; ++nf) {
                    int gcol = col0 + wn * 64 + nf * 16 + r;
                    Crow[gcol] = acc[mf][nf][rr] * scl + bv[nf];
                }
            }
        }
    }
}

// ---------------------------------------------------------------------------
// FAVOR+ features (phiK): per block one bh, [128 t x 256 m]. v3 phase A.
// Writes phi as f16-HI ONLY (verified R13). Dynamic LDS 66048. (unchanged)
// ---------------------------------------------------------------------------
__global__ __launch_bounds__(256) void favor_mfma(const unsigned int* __restrict__ Xpk,
                                                  const unsigned short* __restrict__ projh,
                                                  unsigned short* __restrict__ phiH)
{
    extern __shared__ char smem[];
    float* xns = (float*)(smem + 65536);

    const int bh = blockIdx.y;
    const int b = bh >> 4, h = bh & 15;
    const int t0 = blockIdx.x * 128;
    const int tid = threadIdx.x;
    const int w = tid >> 6, lane = tid & 63;
    const int r = lane & 15, q = lane >> 4;

    const unsigned int* Xb = Xpk + ((size_t)b * TT + t0) * 1024 + h * 64;
    const unsigned short* Ph = projh + (size_t)h * 16384;

#pragma unroll
    for (int i = 0; i < 8; i++) {
        int s = tid + i * 256;
        int row = s >> 4, c = s & 15;
        GL2LDS16(Xb + (size_t)row * 1024 + (c ^ (row & 7)) * 4,
                 smem + (i * 256 + w * 64) * 16);
    }
#pragma unroll
    for (int i = 0; i < 8; i++) {
        int s = tid + i * 256;
        int row = s >> 3, c = s & 7;
        GL2LDS16(Ph + (size_t)row * 64 + (c ^ (row & 7)) * 8,
                 smem + 32768 + (i * 256 + w * 64) * 16);
    }
    asm volatile("s_waitcnt vmcnt(0)" ::: "memory");
    __builtin_amdgcn_s_barrier();

    {
        int row = tid >> 1, hf = tid & 1;
        float s = 0.f;
#pragma unroll
        for (int j = 0; j < 8; j++) {
            int pos = hf * 8 + (j ^ (row & 7));
            uint4 d4 = *(const uint4*)(smem + row * 256 + pos * 16);
            const unsigned* du = (const unsigned*)&d4;
#pragma unroll
            for (int e = 0; e < 4; e++) {
                float v = f16tof(du[e] & 0xffffu) + f16tof(du[e] >> 16);
                s += v * v;
            }
        }
        s += __shfl_xor(s, 1, 64);
        if (hf == 0) xns[row] = s;
    }

    f32x4 acc[2][16];
#pragma unroll
    for (int i = 0; i < 2; i++)
#pragma unroll
        for (int j = 0; j < 16; j++) acc[i][j] = (f32x4){0.f, 0.f, 0.f, 0.f};

#pragma unroll
    for (int ks = 0; ks < 4; ks++) {
        const int row0r = w * 32 + r;
        const int row1r = w * 32 + 16 + r;
        f16x8 a0 = *(const f16x8*)(smem + row0r * 256 + ((ks * 4 + q) ^ (row0r & 7)) * 16);
        f16x8 a1 = *(const f16x8*)(smem + row1r * 256 + ((ks * 4 + q) ^ (row1r & 7)) * 16);
        const int w8 = ks * 4 + q;
#pragma unroll
        for (int j = 0; j < 16; j++) {
            int rb = j * 16 + r;
            uint2 bv = *(const uint2*)(smem + 32768 + rb * 128
                                       + (((w8 >> 1) ^ (rb & 7)) * 16) + (w8 & 1) * 8);
            f16x8 bf = dup8(bv);
            acc[0][j] = __builtin_amdgcn_mfma_f32_16x16x32_f16(a0, bf, acc[0][j], 0, 0, 0);
            acc[1][j] = __builtin_amdgcn_mfma_f32_16x16x32_f16(a1, bf, acc[1][j], 0, 0, 0);
        }
    }

    unsigned short* outp = phiH + ((size_t)bh * TT + t0) * MM;
#pragma unroll
    for (int i = 0; i < 2; i++) {
#pragma unroll
        for (int rr = 0; rr < 4; rr++) {
            float mx = acc[i][0][rr];
#pragma unroll
            for (int j = 1; j < 16; j++) mx = fmaxf(mx, acc[i][j][rr]);
            mx = fmaxf(mx, __shfl_xor(mx, 1, 64));
            mx = fmaxf(mx, __shfl_xor(mx, 2, 64));
            mx = fmaxf(mx, __shfl_xor(mx, 4, 64));
            mx = fmaxf(mx, __shfl_xor(mx, 8, 64));
            const int row = w * 32 + i * 16 + q * 4 + rr;
            const float base = -mx - 0.5f * xns[row];
            unsigned short* orow = outp + (size_t)row * MM + r;
#pragma unroll
            for (int j = 0; j < 16; j++) {
                float val = (__expf(acc[i][j][rr] + base) + FEPS) * 0.0625f;
                orow[j * 16] = f16bits((_Float16)val);
            }
        }
    }
}

// ---------------------------------------------------------------------------
// kv_mfma v4 (verified R21): V pre-packed u32; storeV verbatim. (unchanged)
// ---------------------------------------------------------------------------
__global__ __launch_bounds__(256) void kv_mfma(const unsigned short* __restrict__ phiH,
                                               const unsigned int* __restrict__ V,
                                               float* __restrict__ KVp)
{
    const int split = blockIdx.x;        // 0..7
    const int bh = blockIdx.y;           // 0..31
    const int b = bh >> 4, h = bh & 15;
    const int tid = threadIdx.x;
    const int w = tid >> 6, lane = tid & 63;
    const int r = lane & 15, q = lane >> 4;

    extern __shared__ char smem[];
    unsigned int* Vl0 = (unsigned int*)(smem + 49152);
    unsigned int* Vl1 = (unsigned int*)(smem + 57600);

    const unsigned short* pb = phiH + ((size_t)bh * TT + split * 512) * MM;
    const unsigned int* vb = V + ((size_t)b * TT + split * 512) * DD + h * DK;

    f32x4 acc[4][5];
#pragma unroll
    for (int i = 0; i < 4; i++)
#pragma unroll
        for (int j = 0; j < 5; j++) acc[i][j] = (f32x4){0.f, 0.f, 0.f, 0.f};

    const unsigned oc = (r == 0) ? 0x00003C00u : 0u;
    union { unsigned u[4]; f16x8 f; } onesu;
    onesu.u[0] = oc; onesu.u[1] = oc; onesu.u[2] = oc; onesu.u[3] = oc;
    const f16x8 ones = onesu.f;

    auto stPhi = [&](int ck, int buf) {
        char* base = smem + buf * 16384;
#pragma unroll
        for (int i = 0; i < 4; i++) {
            int s = tid + i * 256;
            int row = s >> 5, c = s & 31;
            GL2LDS16(pb + (size_t)(ck * 32 + row) * MM + ((c - row) & 31) * 8,
                     base + (i * 256 + w * 64) * 16);
        }
    };
    auto loadV = [&](unsigned (&vg)[8], int ck) {
#pragma unroll
        for (int i = 0; i < 8; i++)
            vg[i] = vb[(size_t)(ck * 32 + 4 * i + w) * DD + lane];
    };
    auto storeV = [&](unsigned (&vg)[8], unsigned int* VlB) {
#pragma unroll
        for (int i = 0; i < 8; i++)
            VlB[(4 * i + w) * 66 + lane] = vg[i];
    };
    auto compute = [&](int bufc, const unsigned int* VlB) {
        const char* PlB = smem + bufc * 16384;
#pragma unroll
        for (int kw = 0; kw < 2; ++kw) {
            f16x8 af[4];
#pragma unroll
            for (int mq = 0; mq < 4; ++mq) {
                const int m = w * 64 + mq * 16 + r;
                const int mc = m >> 3, mo = (m & 7) * 2;
                unsigned pk[2];
#pragma unroll
                for (int jj = 0; jj < 2; ++jj) {
                    int ta = kw * 16 + q * 4 + jj * 2;
                    unsigned p0 = *(const unsigned short*)
                        (PlB + ta * 512 + ((mc + ta) & 31) * 16 + mo);
                    unsigned p1 = *(const unsigned short*)
                        (PlB + (ta + 1) * 512 + ((mc + ta + 1) & 31) * 16 + mo);
                    pk[jj] = p0 | (p1 << 16);
                }
                uint2 pv; pv.x = pk[0]; pv.y = pk[1];
                af[mq] = dup8(pv);
            }
#pragma unroll
            for (int ct = 0; ct < 4; ++ct) {
                union { unsigned u[4]; f16x8 f; } bv;
#pragma unroll
                for (int j = 0; j < 4; j++) {
                    int t = kw * 16 + q * 4 + j;
                    bv.u[j] = VlB[t * 66 + ct * 16 + r];
                }
#pragma unroll
                for (int mq = 0; mq < 4; ++mq)
                    acc[mq][ct] = __builtin_amdgcn_mfma_f32_16x16x32_f16(
                        af[mq], bv.f, acc[mq][ct], 0, 0, 0);
            }
#pragma unroll
            for (int mq = 0; mq < 4; ++mq)
                acc[mq][4] = __builtin_amdgcn_mfma_f32_16x16x32_f16(
                    af[mq], ones, acc[mq][4], 0, 0, 0);
        }
    };

    unsigned vgA[8], vgB[8];

    stPhi(0, 0);
    stPhi(1, 1);
    loadV(vgA, 0);
    loadV(vgB, 1);
    asm volatile("s_waitcnt vmcnt(8)" ::: "memory");
    __builtin_amdgcn_sched_barrier(0);
    storeV(vgA, Vl0);

    int bufc = 0;
    for (int c = 0; c < 16; c += 2) {
        {
            __builtin_amdgcn_s_barrier();
            const int nc = (c + 2 <= 15) ? c + 2 : 15;
            int bp = bufc + 2; if (bp >= 3) bp -= 3;
            stPhi(nc, bp);
            asm volatile("s_waitcnt vmcnt(4)" ::: "memory");
            __builtin_amdgcn_sched_barrier(0);
            storeV(vgB, Vl1);
            loadV(vgA, nc);
            asm volatile("s_waitcnt lgkmcnt(0)" ::: "memory");
            __builtin_amdgcn_s_barrier();
            compute(bufc, Vl0);
            bufc = (bufc == 2) ? 0 : bufc + 1;
        }
        {
            __builtin_amdgcn_s_barrier();
            const int nc = (c + 3 <= 15) ? c + 3 : 15;
            int bp = bufc + 2; if (bp >= 3) bp -= 3;
            stPhi(nc, bp);
            asm volatile("s_waitcnt vmcnt(4)" ::: "memory");
            __builtin_amdgcn_sched_barrier(0);
            storeV(vgA, Vl0);
            loadV(vgB, nc);
            asm volatile("s_waitcnt lgkmcnt(0)" ::: "memory");
            __builtin_amdgcn_s_barrier();
            compute(bufc, Vl1);
            bufc = (bufc == 2) ? 0 : bufc + 1;
        }
    }
    asm volatile("s_waitcnt vmcnt(0)" ::: "memory");

    float* o = KVp + (((size_t)split * 32 + bh) * MM) * 68;
#pragma unroll
    for (int mq = 0; mq < 4; ++mq) {
#pragma unroll
        for (int reg = 0; reg < 4; ++reg) {
            int m = w * 64 + mq * 16 + q * 4 + reg;
#pragma unroll
            for (int ct = 0; ct < 4; ++ct)
                o[(size_t)m * 68 + ct * 16 + r] = acc[mq][ct][reg];
            if (r < 4)
                o[(size_t)m * 68 + 64 + r] = acc[mq][4][reg];
        }
    }
}

// ---------------------------------------------------------------------------
// kv_reduce (8 splits): KVt16[bh][plane(2)][c(68)][m(256)]. (unchanged)
// ---------------------------------------------------------------------------
__global__ __launch_bounds__(256) void kv_reduce(const float* __restrict__ KVp,
                                                 unsigned short* __restrict__ KVt16)
{
    int idx = blockIdx.x * 256 + threadIdx.x;   // 32*256*68 = 557056 exact
    float s = 0.f;
    for (int sp = 0; sp < 8; sp++) s += KVp[(size_t)sp * 32 * MM * 68 + idx];
    int bh = idx / 17408;
    int rm = idx - bh * 17408;
    int m = rm / 68;
    int c = rm - m * 68;
    _Float16 hv = (_Float16)0.f, lv = (_Float16)0.f;
    if (c <= 64) {
        hv = (_Float16)s;
        lv = (_Float16)(s - (float)hv);
    }
    KVt16[((size_t)(bh * 2 + 0) * 68 + c) * 256 + m] = f16bits(hv);
    KVt16[((size_t)(bh * 2 + 1) * 68 + c) * 256 + m] = f16bits(lv);
}

// ---------------------------------------------------------------------------
// FUSED favor(Q) + attn_out v4 (verified R14/R15). (unchanged)
// ---------------------------------------------------------------------------
__global__ __launch_bounds__(256, 2) void favor_attn(
    const unsigned int* __restrict__ Xpk,
    const unsigned short* __restrict__ projh,
    const unsigned short* __restrict__ KVt16,
    unsigned short* __restrict__ mout)
{
    extern __shared__ char smem[];
    unsigned short* Bt0 = (unsigned short*)(smem + 32768);   // [80][136]
    unsigned short* Bt1 = (unsigned short*)(smem + 54528);   // [80][136]
    float* xns          = (float*)(smem + 76288);            // [128]

    const int bh = blockIdx.y;
    const int b = bh >> 4, h = bh & 15;
    const int t0 = blockIdx.x * 128;
    const int tid = threadIdx.x;
    const int w = tid >> 6, lane = tid & 63;
    const int r = lane & 15, q = lane >> 4;

    const unsigned int* Xb = Xpk + ((size_t)b * TT + t0) * 1024 + h * 64;
    const unsigned short* Ph = projh + (size_t)h * 16384;

#pragma unroll
    for (int i = 0; i < 8; i++) {
        int s = tid + i * 256;
        int row = s >> 4, c = s & 15;
        GL2LDS16(Xb + (size_t)row * 1024 + (c ^ (row & 7)) * 4,
                 smem + (i * 256 + w * 64) * 16);
    }
#pragma unroll
    for (int i = 0; i < 8; i++) {
        int s = tid + i * 256;
        int row = s >> 3, c = s & 7;
        GL2LDS16(Ph + (size_t)row * 64 + (c ^ (row & 7)) * 8,
                 smem + 32768 + (i * 256 + w * 64) * 16);
    }
    asm volatile("s_waitcnt vmcnt(0)" ::: "memory");
    __builtin_amdgcn_s_barrier();

    uint2 rgA[10], rgB[10];
    auto issueBt = [&](uint2 (&rg)[10], int c) {
#pragma unroll
        for (int i = 0; i < 10; i++) {
            int s = tid + i * 256;
            int p = (s >= 1280) ? 1 : 0;
            int s2 = s - p * 1280;
            int rr = s2 >> 4, qq = (s2 & 15) * 4;
            int rc = (rr < 68) ? rr : 0;
            rg[i] = *(const uint2*)(KVt16 + ((size_t)(bh * 2 + p) * 68 + rc) * 256 + c * 64 + qq);
        }
    };
    issueBt(rgA, 0);
    issueBt(rgB, 1);

    {
        int row = tid >> 1, hf = tid & 1;
        float s = 0.f;
#pragma unroll
        for (int j = 0; j < 8; j++) {
            int pos = hf * 8 + (j ^ (row & 7));
            uint4 d4 = *(const uint4*)(smem + row * 256 + pos * 16);
            const unsigned* du = (const unsigned*)&d4;
#pragma unroll
            for (int e = 0; e < 4; e++) {
                float v = f16tof(du[e] & 0xffffu) + f16tof(du[e] >> 16);
                s += v * v;
            }
        }
        s += __shfl_xor(s, 1, 64);
        if (hf == 0) xns[row] = s;
    }

    f32x4 facc[2][16];
#pragma unroll
    for (int i = 0; i < 2; i++)
#pragma unroll
        for (int j = 0; j < 16; j++) facc[i][j] = (f32x4){0.f, 0.f, 0.f, 0.f};

#pragma unroll
    for (int ks = 0; ks < 4; ks++) {
        const int row0r = w * 32 + r;
        const int row1r = w * 32 + 16 + r;
        f16x8 a0 = *(const f16x8*)(smem + row0r * 256 + ((ks * 4 + q) ^ (row0r & 7)) * 16);
        f16x8 a1 = *(const f16x8*)(smem + row1r * 256 + ((ks * 4 + q) ^ (row1r & 7)) * 16);
        const int w8 = ks * 4 + q;
#pragma unroll
        for (int j = 0; j < 16; j++) {
            int rb = j * 16 + r;
            uint2 bv = *(const uint2*)(smem + 32768 + rb * 128
                                       + (((w8 >> 1) ^ (rb & 7)) * 16) + (w8 & 1) * 8);
            f16x8 bf = dup8(bv);
            facc[0][j] = __builtin_amdgcn_mfma_f32_16x16x32_f16(a0, bf, facc[0][j], 0, 0, 0);
            facc[1][j] = __builtin_amdgcn_mfma_f32_16x16x32_f16(a1, bf, facc[1][j], 0, 0, 0);
        }
    }
    __builtin_amdgcn_s_barrier();   // PB reads done; Bt may overwrite it

    float base[2][4];
#pragma unroll
    for (int i = 0; i < 2; i++) {
#pragma unroll
        for (int rr = 0; rr < 4; rr++) {
            float mx = facc[i][0][rr];
#pragma unroll
            for (int j = 1; j < 16; j++) mx = fmaxf(mx, facc[i][j][rr]);
            mx = fmaxf(mx, __shfl_xor(mx, 1, 64));
            mx = fmaxf(mx, __shfl_xor(mx, 2, 64));
            mx = fmaxf(mx, __shfl_xor(mx, 4, 64));
            mx = fmaxf(mx, __shfl_xor(mx, 8, 64));
            const int row = w * 32 + i * 16 + q * 4 + rr;
            base[i][rr] = -mx - 0.5f * xns[row];
        }
    }

    f32x4 aacc[2][5];
#pragma unroll
    for (int i = 0; i < 2; i++)
#pragma unroll
        for (int j = 0; j < 5; j++) aacc[i][j] = (f32x4){0.f, 0.f, 0.f, 0.f};

    const int bFr = r * 136 + q * 8;

    auto writeBt = [&](uint2 (&rg)[10], unsigned short* Bt) {
#pragma unroll
        for (int i = 0; i < 10; i++) {
            int s = tid + i * 256;
            int p = (s >= 1280) ? 1 : 0;
            int s2 = s - p * 1280;
            int rr = s2 >> 4, qq = (s2 & 15) * 4;
            uint2 v = (rr < 68) ? rg[i] : make_uint2(0u, 0u);
            *(uint2*)&Bt[rr * 136 + p * 64 + qq] = v;
        }
    };
    auto writePhi = [&](int c) {                   // hi-only phi store (R14)
#pragma unroll
        for (int i = 0; i < 2; i++) {
#pragma unroll
            for (int jj = 0; jj < 4; jj++) {
#pragma unroll
                for (int rr = 0; rr < 4; rr++) {
                    float ph = (__expf(facc[i][c * 4 + jj][rr] + base[i][rr]) + FEPS) * 0.0625f;
                    int row = w * 32 + i * 16 + q * 4 + rr;
                    int mc = jj * 16 + r;
                    int ch = (mc >> 3) ^ (row & 7);
                    char* rbase = smem + row * 256;
                    *(unsigned short*)(rbase + ch * 16 + (mc & 7) * 2) =
                        f16bits((_Float16)ph);
                }
            }
        }
    };
    auto computeC = [&](unsigned short* Bt) {      // 4 MFMAs per (ks,j) (R14)
#pragma unroll
        for (int ks = 0; ks < 2; ks++) {
            const int row0r = w * 32 + r;
            const int row1r = w * 32 + 16 + r;
            const int ch0 = (ks * 4 + q) ^ (row0r & 7);
            const int ch1 = (ks * 4 + q) ^ (row1r & 7);
            f16x8 ah0 = *(const f16x8*)(smem + row0r * 256 + ch0 * 16);
            f16x8 ah1 = *(const f16x8*)(smem + row1r * 256 + ch1 * 16);
#pragma unroll
            for (int j = 0; j < 5; j++) {
                f16x8 bh_ = *(const f16x8*)&Bt[bFr + j * 16 * 136 + ks * 32];
                f16x8 bl_ = *(const f16x8*)&Bt[bFr + j * 16 * 136 + 64 + ks * 32];
                aacc[0][j] = __builtin_amdgcn_mfma_f32_16x16x32_f16(ah0, bl_, aacc[0][j], 0, 0, 0);
                aacc[0][j] = __builtin_amdgcn_mfma_f32_16x16x32_f16(ah0, bh_, aacc[0][j], 0, 0, 0);
                aacc[1][j] = __builtin_amdgcn_mfma_f32_16x16x32_f16(ah1, bl_, aacc[1][j], 0, 0, 0);
                aacc[1][j] = __builtin_amdgcn_mfma_f32_16x16x32_f16(ah1, bh_, aacc[1][j], 0, 0, 0);
            }
        }
    };

    writeBt(rgA, Bt0);
    asm volatile("s_waitcnt lgkmcnt(0)" ::: "memory");
    __builtin_amdgcn_s_barrier();

    writePhi(0);
    issueBt(rgA, 2);
    writeBt(rgB, Bt1);
    computeC(Bt0);
    asm volatile("s_waitcnt lgkmcnt(0)" ::: "memory");
    __builtin_amdgcn_s_barrier();
    writePhi(1);
    issueBt(rgB, 3);
    writeBt(rgA, Bt0);
    computeC(Bt1);
    asm volatile("s_waitcnt lgkmcnt(0)" ::: "memory");
    __builtin_amdgcn_s_barrier();
    writePhi(2);
    writeBt(rgB, Bt1);
    computeC(Bt0);
    asm volatile("s_waitcnt lgkmcnt(0)" ::: "memory");
    __builtin_amdgcn_s_barrier();
    writePhi(3);
    computeC(Bt1);

    // ---- epilogue: out = num/(den+eps), write merged u16 HI-ONLY ----
    unsigned short* Mp = mout + ((size_t)b * TT + t0) * 1024 + h * DK;
#pragma unroll
    for (int i = 0; i < 2; i++) {
#pragma unroll
        for (int rr = 0; rr < 4; rr++) {
            float den = aacc[i][4][rr];
            den = __shfl(den, lane & 48, 64);
            float dinv = 1.f / (den + FEPS);
            int trow = w * 32 + i * 16 + q * 4 + rr;
#pragma unroll
            for (int j = 0; j < 4; j++) {
                float o = aacc[i][j][rr] * dinv;
                Mp[(size_t)trow * 1024 + j * 16 + r] = f16bits((_Float16)o);
            }
        }
    }
}

// ---------------------------------------------------------------------------
extern "C" void kernel_launch(void* const* d_in, const int* in_sizes, int n_in,
                              void* d_out, int out_size, void* d_ws, size_t ws_size,
                              hipStream_t stream)
{
    (void)in_sizes; (void)n_in; (void)out_size; (void)ws_size;
    const float* x    = (const float*)d_in[0];
    const float* Wq   = (const float*)d_in[1];
    const float* Wk   = (const float*)d_in[2];
    const float* Wv   = (const float*)d_in[3];
    const float* Wo   = (const float*)d_in[4];
    const float* bo   = (const float*)d_in[5];
    const float* proj = (const float*)d_in[6];
    float* out = (float*)d_out;

    float* ws  = (float*)d_ws;
    float* Qs  = ws;                          // 8388608 floats (packed u32 Q)
    float* Ks  = Qs + 8388608ull;             // 8388608 (packed u32 K / m_h u16)
    float* Vb  = Ks + 8388608ull;             // 8388608 (packed u32 V)
    float* phi = Vb + 8388608ull;             // 33554432-float region
    float* KVp = phi + 33554432ull;           // 4456448
    unsigned short* projh = (unsigned short*)(KVp + 4456448ull);  // 262144 f16

    // aliases (lifetime-disjoint with their hosts):
    unsigned short* x_h   = (unsigned short*)phi;  // dead once favor writes phiH
    unsigned short* wqkv  = (unsigned short*)KVp;  // dead before kv_mfma writes
    unsigned short* wo_h  = (unsigned short*)Qs;   // written after Qs is dead
    unsigned short* m_h   = (unsigned short*)Ks;   // written after Ks is dead
    unsigned short* phiH  = (unsigned short*)phi;  // f16-hi phiK
    unsigned short* KVt16 = (unsigned short*)(phi + 20000000ull); // disjoint from live phiH
    unsigned int*   Qpk   = (unsigned int*)Qs;
    unsigned int*   Kpk   = (unsigned int*)Ks;
    unsigned int*   Vpk   = (unsigned int*)Vb;

    dim3 gthr(256);

    split_w3h<<<dim3(3072), gthr, 0, stream>>>(Wq, Wk, Wv, wqkv);
    split_h  <<<dim3(8192), gthr, 0, stream>>>(x, x_h);
    pack_proj<<<dim3(256),  gthr, 0, stream>>>(proj, projh);
    // QKV projection (pure f16-hi): Q,K,V ALL written packed u32 (mask 0b111)
    gemm_h<<<dim3(24, 64), gthr, 49152, stream>>>(
        x_h, wqkv, wqkv + 1048576, wqkv + 2097152,
        Qs, Ks, Vb, nullptr, 0.125f, 0.125f, 1.0f, 0b111);

    favor_mfma<<<dim3(32, 32), gthr, 66048, stream>>>(Kpk, projh, phiH);
    kv_mfma   <<<dim3(8, 32),  gthr, 66048, stream>>>(phiH, Vpk, KVp);
    kv_reduce <<<dim3(2176),   gthr, 0, stream>>>(KVp, KVt16);
    favor_attn<<<dim3(32, 32), gthr, 76800, stream>>>(Qpk, projh, KVt16, m_h);
    split_w3h <<<dim3(1024),   gthr, 0, stream>>>(Wo, Wo, Wo, wo_h);   // into Qs region

    // out projection (pure f16-hi input m_h): f32 output + bias
    gemm_h<<<dim3(8, 64), gthr, 49152, stream>>>(
        m_h, wo_h, wo_h, wo_h, out, out, out, bo, 1.0f, 1.0f, 1.0f, 0);
}

// Round 25
// 235.095 us; speedup vs baseline: 1.0173x; 1.0173x over previous
//
#include <hip/hip_runtime.h>
#include <hip/hip_bf16.h>
#include <math.h>

// Problem constants (FavorPlusAttention): B=2, T=4096, d=1024, h=16, dk=64, m=256
#define BB 2
#define TT 4096
#define DD 1024
#define NH 16
#define DK 64
#define MM 256
#define BT (BB*TT)        // 8192 rows
#define FEPS 1e-6f

typedef _Float16 f16x8 __attribute__((ext_vector_type(8)));
using f32x4 = __attribute__((ext_vector_type(4))) float;

#define GL2LDS16(g, l) __builtin_amdgcn_global_load_lds( \
    (const __attribute__((address_space(1))) void*)(g), \
    (__attribute__((address_space(3))) void*)(l), 16, 0, 0)

static __device__ __forceinline__ unsigned short f16bits(_Float16 v) {
    union { _Float16 f; unsigned short u; } c; c.f = v; return c.u;
}
static __device__ __forceinline__ float f16tof(unsigned u) {
    union { unsigned short s; _Float16 f; } c; c.s = (unsigned short)u; return (float)c.f;
}
// pairwise-duplicate 4 f16 (uint2) -> f16x8  [verified operand pattern]
static __device__ __forceinline__ f16x8 dup8(uint2 v) {
    union { unsigned int u[4]; f16x8 f; } o;
    o.u[0] = __builtin_amdgcn_perm(v.x, v.x, 0x01000100u);
    o.u[1] = __builtin_amdgcn_perm(v.x, v.x, 0x03020302u);
    o.u[2] = __builtin_amdgcn_perm(v.y, v.y, 0x01000100u);
    o.u[3] = __builtin_amdgcn_perm(v.y, v.y, 0x03020302u);
    return o.f;
}

// ---------------------------------------------------------------------------
// hi-only split: src [rows][1024] f32 -> dst [rows][1024] u16 (f16 hi)
// ---------------------------------------------------------------------------
__global__ __launch_bounds__(256) void split_h(const float* __restrict__ src,
                                               unsigned short* __restrict__ dst)
{
    const int rr = blockIdx.x;
    const int c = threadIdx.x * 4;
    float4 v = *(const float4*)(src + (size_t)rr * 1024 + c);
    float f[4] = {v.x, v.y, v.z, v.w};
    union { unsigned short h[4]; uint2 u; } hv;
#pragma unroll
    for (int i = 0; i < 4; i++) hv.h[i] = f16bits((_Float16)f[i]);
    *(uint2*)(dst + (size_t)rr * 1024 + c) = hv.u;
}

// hi-only fp16 weight cast: 3 weights -> [3][1024][1024] f16 (B-operand).
__global__ __launch_bounds__(256) void split_w3h(const float* __restrict__ W0,
                                                 const float* __restrict__ W1,
                                                 const float* __restrict__ W2,
                                                 unsigned short* __restrict__ dst)
{
    const int rr = blockIdx.x;           // 0..3071
    const int wi = rr >> 10, r2 = rr & 1023;
    const float* W = (wi == 0) ? W0 : (wi == 1) ? W1 : W2;
    const int c = threadIdx.x * 4;
    float4 v = *(const float4*)(W + (size_t)r2 * 1024 + c);
    float f[4] = {v.x, v.y, v.z, v.w};
    union { _Float16 h[4]; uint2 u; } hv;
#pragma unroll
    for (int i = 0; i < 4; i++) hv.h[i] = (_Float16)f[i];
    *(uint2*)(dst + (size_t)rr * 1024 + c) = hv.u;
}

// proj f32 [16][256][64] -> f16 hi [16][256][64]
__global__ __launch_bounds__(256) void pack_proj(const float* __restrict__ proj,
                                                 unsigned short* __restrict__ projh)
{
    const int idx = (blockIdx.x * 256 + threadIdx.x) * 4;   // 65536*4 = 262144
    float4 v = *(const float4*)(proj + idx);
    float f[4] = {v.x, v.y, v.z, v.w};
    union { _Float16 h[4]; uint2 u; } hv;
#pragma unroll
    for (int i = 0; i < 4; i++) hv.h[i] = (_Float16)f[i];
    *(uint2*)(projh + idx) = hv.u;
}

// ---------------------------------------------------------------------------
// gemm_h v2 (verified R22, 73.3us QKV / 235.3us total — BEST): pure f16-hi
// GEMM, K-loop unrolled by 2. C = scale*(A_hi@B_hi^T)(+bias). 128x128 tile,
// BK=32, 4 waves, LDS 32 KB, 3 blocks/CU.
// R24 post-mortem: deeper prefetch (3-buf rotation, counted vmcnt) REGRESSED
// (FETCH 98->127 MB): this kernel is L2-locality-bound, and the 2-tile
// burst-load pattern synchronized across XCD-grouped blocks is what keeps
// FETCH near-ideal. Do not stagger the loads. MfmaUtil ~28 is this
// structure's locality ceiling.
// ---------------------------------------------------------------------------
__global__ __launch_bounds__(256, 3) void gemm_h(
    const unsigned short* __restrict__ A,
    const unsigned short* __restrict__ B0, const unsigned short* __restrict__ B1,
    const unsigned short* __restrict__ B2,
    float* __restrict__ C0, float* __restrict__ C1, float* __restrict__ C2,
    const float* __restrict__ bias,
    float sc0, float sc1, float sc2, int packMask)
{
    extern __shared__ char smem[];   // 32768

    // ---- XCD-grouping remap (R11) ----
    const int gx = gridDim.x, gy = gridDim.y;
    const int flat = blockIdx.y * gx + blockIdx.x;
    const int k8 = flat & 7, j8 = flat >> 3;
    const int yy = k8 * (gy >> 3) + j8 / gx;
    const int xx = j8 - (j8 / gx) * gx;

    const int which = xx >> 3;
    const int col0 = (xx & 7) * 128;
    const int row0 = yy * 128;
    const unsigned short* Bp = (which == 0) ? B0 : (which == 1) ? B1 : B2;
    float* Cp = (which == 0) ? C0 : (which == 1) ? C1 : C2;
    const float scl = (which == 0) ? sc0 : (which == 1) ? sc1 : sc2;
    const int packC = (packMask >> which) & 1;

    const int tid = threadIdx.x;             // 0..255
    const int w = tid >> 6, lane = tid & 63;
    const int wm = w >> 1, wn = w & 1;       // 2M x 2N wave grid
    const int r = lane & 15, q = lane >> 4;

    const unsigned short* aP[2];
    const unsigned short* bP[2];
    int dstO[2];
#pragma unroll
    for (int i = 0; i < 2; i++) {
        int s = tid + i * 256;
        int row = s >> 2, c = s & 3;
        aP[i] = A + (size_t)(row0 + row) * 1024 + ((c ^ (row & 3)) * 8);
        bP[i] = Bp + (size_t)(col0 + row) * 1024 + ((c ^ (row & 3)) * 8);
        dstO[i] = (i * 256 + w * 64) * 16;
    }

    auto stA = [&](int buf, int kt) {
        char* base = smem + buf * 8192;
        GL2LDS16(aP[0] + kt * 32, base + dstO[0]);
        GL2LDS16(aP[1] + kt * 32, base + dstO[1]);
    };
    auto stB = [&](int buf, int kt) {
        char* base = smem + 16384 + buf * 8192;
        GL2LDS16(bP[0] + kt * 32, base + dstO[0]);
        GL2LDS16(bP[1] + kt * 32, base + dstO[1]);
    };

    const int aRow = (wm * 64 + r) * 64;     // + mf*1024
    const int bRow = (wn * 64 + r) * 64;     // + nf*1024
    const int kx = (q ^ (r & 3)) * 16;

    f32x4 acc[4][4];
#pragma unroll
    for (int i = 0; i < 4; i++)
#pragma unroll
        for (int j = 0; j < 4; j++) acc[i][j] = (f32x4){0.f, 0.f, 0.f, 0.f};

    // ---- prologue: stage tiles 0 (buf0) and 1 (buf1); drain; barrier ----
    stA(0, 0); stB(0, 0);
    stA(1, 1); stB(1, 1);
    asm volatile("s_waitcnt vmcnt(0)" ::: "memory");
    __builtin_amdgcn_s_barrier();

    for (int t = 0; t < 32; t += 2) {
        const int kt2 = (t + 2 < 32) ? t + 2 : 31;
        const int kt3 = (t + 3 < 32) ? t + 3 : 31;
        f16x8 af0[4], bf0[4], af1[4], bf1[4];
        // read all 8 frags of both tiles (buf0 = tile t, buf1 = tile t+1)
#pragma unroll
        for (int mf = 0; mf < 4; ++mf) {
            af0[mf] = *(const f16x8*)(smem + 0    + aRow + mf * 1024 + kx);
            af1[mf] = *(const f16x8*)(smem + 8192 + aRow + mf * 1024 + kx);
        }
#pragma unroll
        for (int nf = 0; nf < 4; ++nf) {
            bf0[nf] = *(const f16x8*)(smem + 16384 + bRow + nf * 1024 + kx);
            bf1[nf] = *(const f16x8*)(smem + 24576 + bRow + nf * 1024 + kx);
        }
        asm volatile("s_waitcnt lgkmcnt(0)" ::: "memory");
        __builtin_amdgcn_sched_barrier(0);
        __builtin_amdgcn_s_barrier();          // all waves done reading both bufs
        stA(0, kt2); stB(0, kt2);              // refill just-read buffers
        stA(1, kt3); stB(1, kt3);
        __builtin_amdgcn_s_setprio(1);
#pragma unroll
        for (int mf = 0; mf < 4; ++mf)
#pragma unroll
            for (int nf = 0; nf < 4; ++nf)
                acc[mf][nf] = __builtin_amdgcn_mfma_f32_16x16x32_f16(
                    af0[mf], bf0[nf], acc[mf][nf], 0, 0, 0);
#pragma unroll
        for (int mf = 0; mf < 4; ++mf)
#pragma unroll
            for (int nf = 0; nf < 4; ++nf)
                acc[mf][nf] = __builtin_amdgcn_mfma_f32_16x16x32_f16(
                    af1[mf], bf1[nf], acc[mf][nf], 0, 0, 0);
        __builtin_amdgcn_s_setprio(0);
        asm volatile("s_waitcnt vmcnt(0)" ::: "memory");   // t+2,t+3 landed
        __builtin_amdgcn_s_barrier();
    }

    // ---- epilogue: C/D layout col = lane&15, row = (lane>>4)*4 + reg ----
    float bv[4];
#pragma unroll
    for (int nf = 0; nf < 4; ++nf) {
        int gcol = col0 + wn * 64 + nf * 16 + r;
        bv[nf] = bias ? bias[gcol] : 0.f;
    }
#pragma unroll
    for (int mf = 0; mf < 4; ++mf) {
        const int grow = row0 + wm * 64 + mf * 16 + q * 4;
#pragma unroll
        for (int rr = 0; rr < 4; ++rr) {
            if (packC) {
                unsigned int* Crow = (unsigned int*)Cp + (size_t)(grow + rr) * 1024;
#pragma unroll
                for (int nf = 0; nf < 4; ++nf) {
                    int gcol = col0 + wn * 64 + nf * 16 + r;
                    float v = acc[mf][nf][rr] * scl;
                    _Float16 hh = (_Float16)v;
                    _Float16 ll = (_Float16)(v - (float)hh);
                    Crow[gcol] = (unsigned int)f16bits(hh)
                               | ((unsigned int)f16bits(ll) << 16);
                }
            } else {
                float* Crow = Cp + (size_t)(grow + rr) * 1024;
#pragma unroll
                for (int nf = 0; nf < 4; ++nf) {
                    int gcol = col0 + wn * 64 + nf * 16 + r;
                    Crow[gcol] = acc[mf][nf][rr] * scl + bv[nf];
                }
            }
        }
    }
}

// ---------------------------------------------------------------------------
// FAVOR+ features (phiK): per block one bh, [128 t x 256 m]. v3 phase A.
// Writes phi as f16-HI ONLY (verified R13). Dynamic LDS 66048. (unchanged)
// ---------------------------------------------------------------------------
__global__ __launch_bounds__(256) void favor_mfma(const unsigned int* __restrict__ Xpk,
                                                  const unsigned short* __restrict__ projh,
                                                  unsigned short* __restrict__ phiH)
{
    extern __shared__ char smem[];
    float* xns = (float*)(smem + 65536);

    const int bh = blockIdx.y;
    const int b = bh >> 4, h = bh & 15;
    const int t0 = blockIdx.x * 128;
    const int tid = threadIdx.x;
    const int w = tid >> 6, lane = tid & 63;
    const int r = lane & 15, q = lane >> 4;

    const unsigned int* Xb = Xpk + ((size_t)b * TT + t0) * 1024 + h * 64;
    const unsigned short* Ph = projh + (size_t)h * 16384;

#pragma unroll
    for (int i = 0; i < 8; i++) {
        int s = tid + i * 256;
        int row = s >> 4, c = s & 15;
        GL2LDS16(Xb + (size_t)row * 1024 + (c ^ (row & 7)) * 4,
                 smem + (i * 256 + w * 64) * 16);
    }
#pragma unroll
    for (int i = 0; i < 8; i++) {
        int s = tid + i * 256;
        int row = s >> 3, c = s & 7;
        GL2LDS16(Ph + (size_t)row * 64 + (c ^ (row & 7)) * 8,
                 smem + 32768 + (i * 256 + w * 64) * 16);
    }
    asm volatile("s_waitcnt vmcnt(0)" ::: "memory");
    __builtin_amdgcn_s_barrier();

    {
        int row = tid >> 1, hf = tid & 1;
        float s = 0.f;
#pragma unroll
        for (int j = 0; j < 8; j++) {
            int pos = hf * 8 + (j ^ (row & 7));
            uint4 d4 = *(const uint4*)(smem + row * 256 + pos * 16);
            const unsigned* du = (const unsigned*)&d4;
#pragma unroll
            for (int e = 0; e < 4; e++) {
                float v = f16tof(du[e] & 0xffffu) + f16tof(du[e] >> 16);
                s += v * v;
            }
        }
        s += __shfl_xor(s, 1, 64);
        if (hf == 0) xns[row] = s;
    }

    f32x4 acc[2][16];
#pragma unroll
    for (int i = 0; i < 2; i++)
#pragma unroll
        for (int j = 0; j < 16; j++) acc[i][j] = (f32x4){0.f, 0.f, 0.f, 0.f};

#pragma unroll
    for (int ks = 0; ks < 4; ks++) {
        const int row0r = w * 32 + r;
        const int row1r = w * 32 + 16 + r;
        f16x8 a0 = *(const f16x8*)(smem + row0r * 256 + ((ks * 4 + q) ^ (row0r & 7)) * 16);
        f16x8 a1 = *(const f16x8*)(smem + row1r * 256 + ((ks * 4 + q) ^ (row1r & 7)) * 16);
        const int w8 = ks * 4 + q;
#pragma unroll
        for (int j = 0; j < 16; j++) {
            int rb = j * 16 + r;
            uint2 bv = *(const uint2*)(smem + 32768 + rb * 128
                                       + (((w8 >> 1) ^ (rb & 7)) * 16) + (w8 & 1) * 8);
            f16x8 bf = dup8(bv);
            acc[0][j] = __builtin_amdgcn_mfma_f32_16x16x32_f16(a0, bf, acc[0][j], 0, 0, 0);
            acc[1][j] = __builtin_amdgcn_mfma_f32_16x16x32_f16(a1, bf, acc[1][j], 0, 0, 0);
        }
    }

    unsigned short* outp = phiH + ((size_t)bh * TT + t0) * MM;
#pragma unroll
    for (int i = 0; i < 2; i++) {
#pragma unroll
        for (int rr = 0; rr < 4; rr++) {
            float mx = acc[i][0][rr];
#pragma unroll
            for (int j = 1; j < 16; j++) mx = fmaxf(mx, acc[i][j][rr]);
            mx = fmaxf(mx, __shfl_xor(mx, 1, 64));
            mx = fmaxf(mx, __shfl_xor(mx, 2, 64));
            mx = fmaxf(mx, __shfl_xor(mx, 4, 64));
            mx = fmaxf(mx, __shfl_xor(mx, 8, 64));
            const int row = w * 32 + i * 16 + q * 4 + rr;
            const float base = -mx - 0.5f * xns[row];
            unsigned short* orow = outp + (size_t)row * MM + r;
#pragma unroll
            for (int j = 0; j < 16; j++) {
                float val = (__expf(acc[i][j][rr] + base) + FEPS) * 0.0625f;
                orow[j * 16] = f16bits((_Float16)val);
            }
        }
    }
}

// ---------------------------------------------------------------------------
// kv_mfma v4 (verified R21): V pre-packed u32; storeV verbatim. (unchanged)
// ---------------------------------------------------------------------------
__global__ __launch_bounds__(256) void kv_mfma(const unsigned short* __restrict__ phiH,
                                               const unsigned int* __restrict__ V,
                                               float* __restrict__ KVp)
{
    const int split = blockIdx.x;        // 0..7
    const int bh = blockIdx.y;           // 0..31
    const int b = bh >> 4, h = bh & 15;
    const int tid = threadIdx.x;
    const int w = tid >> 6, lane = tid & 63;
    const int r = lane & 15, q = lane >> 4;

    extern __shared__ char smem[];
    unsigned int* Vl0 = (unsigned int*)(smem + 49152);
    unsigned int* Vl1 = (unsigned int*)(smem + 57600);

    const unsigned short* pb = phiH + ((size_t)bh * TT + split * 512) * MM;
    const unsigned int* vb = V + ((size_t)b * TT + split * 512) * DD + h * DK;

    f32x4 acc[4][5];
#pragma unroll
    for (int i = 0; i < 4; i++)
#pragma unroll
        for (int j = 0; j < 5; j++) acc[i][j] = (f32x4){0.f, 0.f, 0.f, 0.f};

    const unsigned oc = (r == 0) ? 0x00003C00u : 0u;
    union { unsigned u[4]; f16x8 f; } onesu;
    onesu.u[0] = oc; onesu.u[1] = oc; onesu.u[2] = oc; onesu.u[3] = oc;
    const f16x8 ones = onesu.f;

    auto stPhi = [&](int ck, int buf) {
        char* base = smem + buf * 16384;
#pragma unroll
        for (int i = 0; i < 4; i++) {
            int s = tid + i * 256;
            int row = s >> 5, c = s & 31;
            GL2LDS16(pb + (size_t)(ck * 32 + row) * MM + ((c - row) & 31) * 8,
                     base + (i * 256 + w * 64) * 16);
        }
    };
    auto loadV = [&](unsigned (&vg)[8], int ck) {
#pragma unroll
        for (int i = 0; i < 8; i++)
            vg[i] = vb[(size_t)(ck * 32 + 4 * i + w) * DD + lane];
    };
    auto storeV = [&](unsigned (&vg)[8], unsigned int* VlB) {
#pragma unroll
        for (int i = 0; i < 8; i++)
            VlB[(4 * i + w) * 66 + lane] = vg[i];
    };
    auto compute = [&](int bufc, const unsigned int* VlB) {
        const char* PlB = smem + bufc * 16384;
#pragma unroll
        for (int kw = 0; kw < 2; ++kw) {
            f16x8 af[4];
#pragma unroll
            for (int mq = 0; mq < 4; ++mq) {
                const int m = w * 64 + mq * 16 + r;
                const int mc = m >> 3, mo = (m & 7) * 2;
                unsigned pk[2];
#pragma unroll
                for (int jj = 0; jj < 2; ++jj) {
                    int ta = kw * 16 + q * 4 + jj * 2;
                    unsigned p0 = *(const unsigned short*)
                        (PlB + ta * 512 + ((mc + ta) & 31) * 16 + mo);
                    unsigned p1 = *(const unsigned short*)
                        (PlB + (ta + 1) * 512 + ((mc + ta + 1) & 31) * 16 + mo);
                    pk[jj] = p0 | (p1 << 16);
                }
                uint2 pv; pv.x = pk[0]; pv.y = pk[1];
                af[mq] = dup8(pv);
            }
#pragma unroll
            for (int ct = 0; ct < 4; ++ct) {
                union { unsigned u[4]; f16x8 f; } bv;
#pragma unroll
                for (int j = 0; j < 4; j++) {
                    int t = kw * 16 + q * 4 + j;
                    bv.u[j] = VlB[t * 66 + ct * 16 + r];
                }
#pragma unroll
                for (int mq = 0; mq < 4; ++mq)
                    acc[mq][ct] = __builtin_amdgcn_mfma_f32_16x16x32_f16(
                        af[mq], bv.f, acc[mq][ct], 0, 0, 0);
            }
#pragma unroll
            for (int mq = 0; mq < 4; ++mq)
                acc[mq][4] = __builtin_amdgcn_mfma_f32_16x16x32_f16(
                    af[mq], ones, acc[mq][4], 0, 0, 0);
        }
    };

    unsigned vgA[8], vgB[8];

    stPhi(0, 0);
    stPhi(1, 1);
    loadV(vgA, 0);
    loadV(vgB, 1);
    asm volatile("s_waitcnt vmcnt(8)" ::: "memory");
    __builtin_amdgcn_sched_barrier(0);
    storeV(vgA, Vl0);

    int bufc = 0;
    for (int c = 0; c < 16; c += 2) {
        {
            __builtin_amdgcn_s_barrier();
            const int nc = (c + 2 <= 15) ? c + 2 : 15;
            int bp = bufc + 2; if (bp >= 3) bp -= 3;
            stPhi(nc, bp);
            asm volatile("s_waitcnt vmcnt(4)" ::: "memory");
            __builtin_amdgcn_sched_barrier(0);
            storeV(vgB, Vl1);
            loadV(vgA, nc);
            asm volatile("s_waitcnt lgkmcnt(0)" ::: "memory");
            __builtin_amdgcn_s_barrier();
            compute(bufc, Vl0);
            bufc = (bufc == 2) ? 0 : bufc + 1;
        }
        {
            __builtin_amdgcn_s_barrier();
            const int nc = (c + 3 <= 15) ? c + 3 : 15;
            int bp = bufc + 2; if (bp >= 3) bp -= 3;
            stPhi(nc, bp);
            asm volatile("s_waitcnt vmcnt(4)" ::: "memory");
            __builtin_amdgcn_sched_barrier(0);
            storeV(vgA, Vl0);
            loadV(vgB, nc);
            asm volatile("s_waitcnt lgkmcnt(0)" ::: "memory");
            __builtin_amdgcn_s_barrier();
            compute(bufc, Vl1);
            bufc = (bufc == 2) ? 0 : bufc + 1;
        }
    }
    asm volatile("s_waitcnt vmcnt(0)" ::: "memory");

    float* o = KVp + (((size_t)split * 32 + bh) * MM) * 68;
#pragma unroll
    for (int mq = 0; mq < 4; ++mq) {
#pragma unroll
        for (int reg = 0; reg < 4; ++reg) {
            int m = w * 64 + mq * 16 + q * 4 + reg;
#pragma unroll
            for (int ct = 0; ct < 4; ++ct)
                o[(size_t)m * 68 + ct * 16 + r] = acc[mq][ct][reg];
            if (r < 4)
                o[(size_t)m * 68 + 64 + r] = acc[mq][4][reg];
        }
    }
}

// ---------------------------------------------------------------------------
// kv_reduce (8 splits): KVt16[bh][plane(2)][c(68)][m(256)]. (unchanged)
// ---------------------------------------------------------------------------
__global__ __launch_bounds__(256) void kv_reduce(const float* __restrict__ KVp,
                                                 unsigned short* __restrict__ KVt16)
{
    int idx = blockIdx.x * 256 + threadIdx.x;   // 32*256*68 = 557056 exact
    float s = 0.f;
    for (int sp = 0; sp < 8; sp++) s += KVp[(size_t)sp * 32 * MM * 68 + idx];
    int bh = idx / 17408;
    int rm = idx - bh * 17408;
    int m = rm / 68;
    int c = rm - m * 68;
    _Float16 hv = (_Float16)0.f, lv = (_Float16)0.f;
    if (c <= 64) {
        hv = (_Float16)s;
        lv = (_Float16)(s - (float)hv);
    }
    KVt16[((size_t)(bh * 2 + 0) * 68 + c) * 256 + m] = f16bits(hv);
    KVt16[((size_t)(bh * 2 + 1) * 68 + c) * 256 + m] = f16bits(lv);
}

// ---------------------------------------------------------------------------
// FUSED favor(Q) + attn_out v4 (verified R14/R15). (unchanged)
// ---------------------------------------------------------------------------
__global__ __launch_bounds__(256, 2) void favor_attn(
    const unsigned int* __restrict__ Xpk,
    const unsigned short* __restrict__ projh,
    const unsigned short* __restrict__ KVt16,
    unsigned short* __restrict__ mout)
{
    extern __shared__ char smem[];
    unsigned short* Bt0 = (unsigned short*)(smem + 32768);   // [80][136]
    unsigned short* Bt1 = (unsigned short*)(smem + 54528);   // [80][136]
    float* xns          = (float*)(smem + 76288);            // [128]

    const int bh = blockIdx.y;
    const int b = bh >> 4, h = bh & 15;
    const int t0 = blockIdx.x * 128;
    const int tid = threadIdx.x;
    const int w = tid >> 6, lane = tid & 63;
    const int r = lane & 15, q = lane >> 4;

    const unsigned int* Xb = Xpk + ((size_t)b * TT + t0) * 1024 + h * 64;
    const unsigned short* Ph = projh + (size_t)h * 16384;

#pragma unroll
    for (int i = 0; i < 8; i++) {
        int s = tid + i * 256;
        int row = s >> 4, c = s & 15;
        GL2LDS16(Xb + (size_t)row * 1024 + (c ^ (row & 7)) * 4,
                 smem + (i * 256 + w * 64) * 16);
    }
#pragma unroll
    for (int i = 0; i < 8; i++) {
        int s = tid + i * 256;
        int row = s >> 3, c = s & 7;
        GL2LDS16(Ph + (size_t)row * 64 + (c ^ (row & 7)) * 8,
                 smem + 32768 + (i * 256 + w * 64) * 16);
    }
    asm volatile("s_waitcnt vmcnt(0)" ::: "memory");
    __builtin_amdgcn_s_barrier();

    uint2 rgA[10], rgB[10];
    auto issueBt = [&](uint2 (&rg)[10], int c) {
#pragma unroll
        for (int i = 0; i < 10; i++) {
            int s = tid + i * 256;
            int p = (s >= 1280) ? 1 : 0;
            int s2 = s - p * 1280;
            int rr = s2 >> 4, qq = (s2 & 15) * 4;
            int rc = (rr < 68) ? rr : 0;
            rg[i] = *(const uint2*)(KVt16 + ((size_t)(bh * 2 + p) * 68 + rc) * 256 + c * 64 + qq);
        }
    };
    issueBt(rgA, 0);
    issueBt(rgB, 1);

    {
        int row = tid >> 1, hf = tid & 1;
        float s = 0.f;
#pragma unroll
        for (int j = 0; j < 8; j++) {
            int pos = hf * 8 + (j ^ (row & 7));
            uint4 d4 = *(const uint4*)(smem + row * 256 + pos * 16);
            const unsigned* du = (const unsigned*)&d4;
#pragma unroll
            for (int e = 0; e < 4; e++) {
                float v = f16tof(du[e] & 0xffffu) + f16tof(du[e] >> 16);
                s += v * v;
            }
        }
        s += __shfl_xor(s, 1, 64);
        if (hf == 0) xns[row] = s;
    }

    f32x4 facc[2][16];
#pragma unroll
    for (int i = 0; i < 2; i++)
#pragma unroll
        for (int j = 0; j < 16; j++) facc[i][j] = (f32x4){0.f, 0.f, 0.f, 0.f};

#pragma unroll
    for (int ks = 0; ks < 4; ks++) {
        const int row0r = w * 32 + r;
        const int row1r = w * 32 + 16 + r;
        f16x8 a0 = *(const f16x8*)(smem + row0r * 256 + ((ks * 4 + q) ^ (row0r & 7)) * 16);
        f16x8 a1 = *(const f16x8*)(smem + row1r * 256 + ((ks * 4 + q) ^ (row1r & 7)) * 16);
        const int w8 = ks * 4 + q;
#pragma unroll
        for (int j = 0; j < 16; j++) {
            int rb = j * 16 + r;
            uint2 bv = *(const uint2*)(smem + 32768 + rb * 128
                                       + (((w8 >> 1) ^ (rb & 7)) * 16) + (w8 & 1) * 8);
            f16x8 bf = dup8(bv);
            facc[0][j] = __builtin_amdgcn_mfma_f32_16x16x32_f16(a0, bf, facc[0][j], 0, 0, 0);
            facc[1][j] = __builtin_amdgcn_mfma_f32_16x16x32_f16(a1, bf, facc[1][j], 0, 0, 0);
        }
    }
    __builtin_amdgcn_s_barrier();   // PB reads done; Bt may overwrite it

    float base[2][4];
#pragma unroll
    for (int i = 0; i < 2; i++) {
#pragma unroll
        for (int rr = 0; rr < 4; rr++) {
            float mx = facc[i][0][rr];
#pragma unroll
            for (int j = 1; j < 16; j++) mx = fmaxf(mx, facc[i][j][rr]);
            mx = fmaxf(mx, __shfl_xor(mx, 1, 64));
            mx = fmaxf(mx, __shfl_xor(mx, 2, 64));
            mx = fmaxf(mx, __shfl_xor(mx, 4, 64));
            mx = fmaxf(mx, __shfl_xor(mx, 8, 64));
            const int row = w * 32 + i * 16 + q * 4 + rr;
            base[i][rr] = -mx - 0.5f * xns[row];
        }
    }

    f32x4 aacc[2][5];
#pragma unroll
    for (int i = 0; i < 2; i++)
#pragma unroll
        for (int j = 0; j < 5; j++) aacc[i][j] = (f32x4){0.f, 0.f, 0.f, 0.f};

    const int bFr = r * 136 + q * 8;

    auto writeBt = [&](uint2 (&rg)[10], unsigned short* Bt) {
#pragma unroll
        for (int i = 0; i < 10; i++) {
            int s = tid + i * 256;
            int p = (s >= 1280) ? 1 : 0;
            int s2 = s - p * 1280;
            int rr = s2 >> 4, qq = (s2 & 15) * 4;
            uint2 v = (rr < 68) ? rg[i] : make_uint2(0u, 0u);
            *(uint2*)&Bt[rr * 136 + p * 64 + qq] = v;
        }
    };
    auto writePhi = [&](int c) {                   // hi-only phi store (R14)
#pragma unroll
        for (int i = 0; i < 2; i++) {
#pragma unroll
            for (int jj = 0; jj < 4; jj++) {
#pragma unroll
                for (int rr = 0; rr < 4; rr++) {
                    float ph = (__expf(facc[i][c * 4 + jj][rr] + base[i][rr]) + FEPS) * 0.0625f;
                    int row = w * 32 + i * 16 + q * 4 + rr;
                    int mc = jj * 16 + r;
                    int ch = (mc >> 3) ^ (row & 7);
                    char* rbase = smem + row * 256;
                    *(unsigned short*)(rbase + ch * 16 + (mc & 7) * 2) =
                        f16bits((_Float16)ph);
                }
            }
        }
    };
    auto computeC = [&](unsigned short* Bt) {      // 4 MFMAs per (ks,j) (R14)
#pragma unroll
        for (int ks = 0; ks < 2; ks++) {
            const int row0r = w * 32 + r;
            const int row1r = w * 32 + 16 + r;
            const int ch0 = (ks * 4 + q) ^ (row0r & 7);
            const int ch1 = (ks * 4 + q) ^ (row1r & 7);
            f16x8 ah0 = *(const f16x8*)(smem + row0r * 256 + ch0 * 16);
            f16x8 ah1 = *(const f16x8*)(smem + row1r * 256 + ch1 * 16);
#pragma unroll
            for (int j = 0; j < 5; j++) {
                f16x8 bh_ = *(const f16x8*)&Bt[bFr + j * 16 * 136 + ks * 32];
                f16x8 bl_ = *(const f16x8*)&Bt[bFr + j * 16 * 136 + 64 + ks * 32];
                aacc[0][j] = __builtin_amdgcn_mfma_f32_16x16x32_f16(ah0, bl_, aacc[0][j], 0, 0, 0);
                aacc[0][j] = __builtin_amdgcn_mfma_f32_16x16x32_f16(ah0, bh_, aacc[0][j], 0, 0, 0);
                aacc[1][j] = __builtin_amdgcn_mfma_f32_16x16x32_f16(ah1, bl_, aacc[1][j], 0, 0, 0);
                aacc[1][j] = __builtin_amdgcn_mfma_f32_16x16x32_f16(ah1, bh_, aacc[1][j], 0, 0, 0);
            }
        }
    };

    writeBt(rgA, Bt0);
    asm volatile("s_waitcnt lgkmcnt(0)" ::: "memory");
    __builtin_amdgcn_s_barrier();

    writePhi(0);
    issueBt(rgA, 2);
    writeBt(rgB, Bt1);
    computeC(Bt0);
    asm volatile("s_waitcnt lgkmcnt(0)" ::: "memory");
    __builtin_amdgcn_s_barrier();
    writePhi(1);
    issueBt(rgB, 3);
    writeBt(rgA, Bt0);
    computeC(Bt1);
    asm volatile("s_waitcnt lgkmcnt(0)" ::: "memory");
    __builtin_amdgcn_s_barrier();
    writePhi(2);
    writeBt(rgB, Bt1);
    computeC(Bt0);
    asm volatile("s_waitcnt lgkmcnt(0)" ::: "memory");
    __builtin_amdgcn_s_barrier();
    writePhi(3);
    computeC(Bt1);

    // ---- epilogue: out = num/(den+eps), write merged u16 HI-ONLY ----
    unsigned short* Mp = mout + ((size_t)b * TT + t0) * 1024 + h * DK;
#pragma unroll
    for (int i = 0; i < 2; i++) {
#pragma unroll
        for (int rr = 0; rr < 4; rr++) {
            float den = aacc[i][4][rr];
            den = __shfl(den, lane & 48, 64);
            float dinv = 1.f / (den + FEPS);
            int trow = w * 32 + i * 16 + q * 4 + rr;
#pragma unroll
            for (int j = 0; j < 4; j++) {
                float o = aacc[i][j][rr] * dinv;
                Mp[(size_t)trow * 1024 + j * 16 + r] = f16bits((_Float16)o);
            }
        }
    }
}

// ---------------------------------------------------------------------------
extern "C" void kernel_launch(void* const* d_in, const int* in_sizes, int n_in,
                              void* d_out, int out_size, void* d_ws, size_t ws_size,
                              hipStream_t stream)
{
    (void)in_sizes; (void)n_in; (void)out_size; (void)ws_size;
    const float* x    = (const float*)d_in[0];
    const float* Wq   = (const float*)d_in[1];
    const float* Wk   = (const float*)d_in[2];
    const float* Wv   = (const float*)d_in[3];
    const float* Wo   = (const float*)d_in[4];
    const float* bo   = (const float*)d_in[5];
    const float* proj = (const float*)d_in[6];
    float* out = (float*)d_out;

    float* ws  = (float*)d_ws;
    float* Qs  = ws;                          // 8388608 floats (packed u32 Q)
    float* Ks  = Qs + 8388608ull;             // 8388608 (packed u32 K / m_h u16)
    float* Vb  = Ks + 8388608ull;             // 8388608 (packed u32 V)
    float* phi = Vb + 8388608ull;             // 33554432-float region
    float* KVp = phi + 33554432ull;           // 4456448
    unsigned short* projh = (unsigned short*)(KVp + 4456448ull);  // 262144 f16

    // aliases (lifetime-disjoint with their hosts):
    unsigned short* x_h   = (unsigned short*)phi;  // dead once favor writes phiH
    unsigned short* wqkv  = (unsigned short*)KVp;  // dead before kv_mfma writes
    unsigned short* wo_h  = (unsigned short*)Qs;   // written after Qs is dead
    unsigned short* m_h   = (unsigned short*)Ks;   // written after Ks is dead
    unsigned short* phiH  = (unsigned short*)phi;  // f16-hi phiK
    unsigned short* KVt16 = (unsigned short*)(phi + 20000000ull); // disjoint from live phiH
    unsigned int*   Qpk   = (unsigned int*)Qs;
    unsigned int*   Kpk   = (unsigned int*)Ks;
    unsigned int*   Vpk   = (unsigned int*)Vb;

    dim3 gthr(256);

    split_w3h<<<dim3(3072), gthr, 0, stream>>>(Wq, Wk, Wv, wqkv);
    split_h  <<<dim3(8192), gthr, 0, stream>>>(x, x_h);
    pack_proj<<<dim3(256),  gthr, 0, stream>>>(proj, projh);
    // QKV projection (pure f16-hi): Q,K,V ALL written packed u32 (mask 0b111)
    gemm_h<<<dim3(24, 64), gthr, 32768, stream>>>(
        x_h, wqkv, wqkv + 1048576, wqkv + 2097152,
        Qs, Ks, Vb, nullptr, 0.125f, 0.125f, 1.0f, 0b111);

    favor_mfma<<<dim3(32, 32), gthr, 66048, stream>>>(Kpk, projh, phiH);
    kv_mfma   <<<dim3(8, 32),  gthr, 66048, stream>>>(phiH, Vpk, KVp);
    kv_reduce <<<dim3(2176),   gthr, 0, stream>>>(KVp, KVt16);
    favor_attn<<<dim3(32, 32), gthr, 76800, stream>>>(Qpk, projh, KVt16, m_h);
    split_w3h <<<dim3(1024),   gthr, 0, stream>>>(Wo, Wo, Wo, wo_h);   // into Qs region

    // out projection (pure f16-hi input m_h): f32 output + bias
    gemm_h<<<dim3(8, 64), gthr, 32768, stream>>>(
        m_h, wo_h, wo_h, wo_h, out, out, out, bo, 1.0f, 1.0f, 1.0f, 0);
}